// Round 7
// baseline (1008.105 us; speedup 1.0000x reference)
//
#include <hip/hip_runtime.h>

// Fixed shapes. Inputs and output are f32 (R4's runtime probe chose f32 and
// produced a finite result; bf16 hard-reads NaN'd). Intermediates fp16,
// accumulation f32. Structure = R4's proven-finite skeleton.
#define T_SEQ 2048
#define DMODEL 2048
#define BSZ 2
#define MROWS (BSZ * T_SEQ)   // 4096 tokens
#define NQKV 4096             // 2048 q | 1024 k | 1024 v
#define NEG_BIG (-1e30f)

typedef __attribute__((ext_vector_type(8))) _Float16 half8;  // 16B, 4 VGPRs
typedef __attribute__((ext_vector_type(4))) float f32x4;     // MFMA acc

__device__ __forceinline__ unsigned short f2bf(float f) {
  unsigned u = __float_as_uint(f);
  unsigned r = (u + 0x7fffu + ((u >> 16) & 1u)) >> 16; // RNE
  return (unsigned short)r;
}
__device__ __forceinline__ float bf2f(unsigned short h) {
  return __uint_as_float(((unsigned)h) << 16);
}

// ---------------- RoPE tables (bf16 round-trip like reference) ----------------
// Written into d_out's first 1 MiB (free until attn overwrites it).
__global__ void build_rope(float* __restrict__ cosT, float* __restrict__ sinT) {
  int t = blockIdx.x;    // 0..2047
  int i = threadIdx.x;   // 0..63
  float inv = (float)pow(10000.0, -((double)(2 * i)) / 128.0);
  float fr = (float)t * inv;
  cosT[t * 64 + i] = bf2f(f2bf(cosf(fr)));
  sinT[t * 64 + i] = bf2f(f2bf(sinf(fr)));
}

// ---------------- x (f32) -> fp16 ----------------
__global__ __launch_bounds__(256) void cvt_x(const float* __restrict__ x,
                                             _Float16* __restrict__ xh) {
  size_t o = ((size_t)blockIdx.x * 256 + threadIdx.x) * 8; // 8,388,608 elems
  float4 v0 = *(const float4*)(x + o);
  float4 v1 = *(const float4*)(x + o + 4);
  half8 r;
  r[0] = (_Float16)v0.x; r[1] = (_Float16)v0.y; r[2] = (_Float16)v0.z; r[3] = (_Float16)v0.w;
  r[4] = (_Float16)v1.x; r[5] = (_Float16)v1.y; r[6] = (_Float16)v1.z; r[7] = (_Float16)v1.w;
  *(half8*)(xh + o) = r;
}

// ---------------- [Wq;Wk;Wv] (f32) -> fused (4096,2048) fp16 ----------------
__global__ __launch_bounds__(256) void cvt_w(const float* __restrict__ Wq,
                                             const float* __restrict__ Wk,
                                             const float* __restrict__ Wv,
                                             _Float16* __restrict__ wh) {
  size_t o = ((size_t)blockIdx.x * 256 + threadIdx.x) * 8; // 8,388,608 elems
  int row = (int)(o >> 11), col = (int)(o & 2047);
  const float* src = (row < 2048) ? (Wq + (size_t)row * 2048)
                    : (row < 3072) ? (Wk + (size_t)(row - 2048) * 2048)
                                   : (Wv + (size_t)(row - 3072) * 2048);
  float4 v0 = *(const float4*)(src + col);
  float4 v1 = *(const float4*)(src + col + 4);
  half8 r;
  r[0] = (_Float16)v0.x; r[1] = (_Float16)v0.y; r[2] = (_Float16)v0.z; r[3] = (_Float16)v0.w;
  r[4] = (_Float16)v1.x; r[5] = (_Float16)v1.y; r[6] = (_Float16)v1.z; r[7] = (_Float16)v1.w;
  *(half8*)(wh + o) = r;
}

// ---------------- NT GEMM: qkv[M,4096] = xh[M,K] * wh[4096,K]^T, fp16 in/out ----------------
// R4 structure: 128x128 tile, BK=32, 4 waves 2x2, f16 MFMA, f32 acc.
__global__ __launch_bounds__(256) void gemm_nt(const _Float16* __restrict__ A,
                                               const _Float16* __restrict__ Bw,
                                               _Float16* __restrict__ C) {
  const int K = DMODEL, N = NQKV;
  __shared__ _Float16 At[128 * 40];
  __shared__ _Float16 Bt[128 * 40];
  int tid = threadIdx.x;
  int lane = tid & 63, w = tid >> 6;
  int wm = w >> 1, wn = w & 1;
  int l15 = lane & 15, quad = lane >> 4;
  int bm = blockIdx.y, bn = blockIdx.x;

  f32x4 acc[4][4];
#pragma unroll
  for (int i = 0; i < 4; i++)
#pragma unroll
    for (int j = 0; j < 4; j++) acc[i][j] = (f32x4){0.f, 0.f, 0.f, 0.f};

  for (int k0 = 0; k0 < K; k0 += 32) {
    __syncthreads();
#pragma unroll
    for (int i = 0; i < 2; i++) {
      int idx = i * 256 + tid;          // 512 chunks of 8 elems per tile (128x32)
      int r = idx >> 2, c = idx & 3;
      *(half8*)&At[r * 40 + c * 8] =
          *(const half8*)(A + (size_t)(bm * 128 + r) * K + k0 + c * 8);
      *(half8*)&Bt[r * 40 + c * 8] =
          *(const half8*)(Bw + (size_t)(bn * 128 + r) * K + k0 + c * 8);
    }
    __syncthreads();
    half8 af[4], bfr[4];
#pragma unroll
    for (int i = 0; i < 4; i++)
      af[i] = *(const half8*)&At[(wm * 64 + i * 16 + l15) * 40 + quad * 8];
#pragma unroll
    for (int j = 0; j < 4; j++)
      bfr[j] = *(const half8*)&Bt[(wn * 64 + j * 16 + l15) * 40 + quad * 8];
#pragma unroll
    for (int i = 0; i < 4; i++)
#pragma unroll
      for (int j = 0; j < 4; j++)
        acc[i][j] = __builtin_amdgcn_mfma_f32_16x16x32_f16(af[i], bfr[j], acc[i][j], 0, 0, 0);
  }
#pragma unroll
  for (int i = 0; i < 4; i++)
#pragma unroll
    for (int j = 0; j < 4; j++)
#pragma unroll
      for (int r = 0; r < 4; r++) {
        int row = bm * 128 + wm * 64 + i * 16 + quad * 4 + r; // C/D: row=quad*4+reg
        int col = bn * 128 + wn * 64 + j * 16 + l15;          //       col=lane&15
        C[(size_t)row * N + col] = (_Float16)acc[i][j][r];
      }
}

// ---------------- RMSNorm + RoPE, IN PLACE on qkv fp16 (q: h<16, k: h>=16) ----------------
__global__ __launch_bounds__(128) void postproc(_Float16* __restrict__ qkv,
                                                const float* __restrict__ cosT,
                                                const float* __restrict__ sinT) {
  int t = blockIdx.x, h = blockIdx.y, b = blockIdx.z;
  int d = threadIdx.x;
  int col = (h < 16) ? (h * 128 + d) : (2048 + (h - 16) * 128 + d);
  size_t idx = ((size_t)(b * T_SEQ + t)) * NQKV + col;
  float v = (float)qkv[idx];
  float ss = v * v;
#pragma unroll
  for (int m = 1; m < 64; m <<= 1) ss += __shfl_xor(ss, m, 64);
  __shared__ float sred[2];
  __shared__ float xs[128];
  if ((threadIdx.x & 63) == 0) sred[threadIdx.x >> 6] = ss;
  __syncthreads();
  float total = sred[0] + sred[1];
  float rn = rsqrtf(total * (1.0f / 128.0f) + 1.1920929e-7f);
  float xn = v * rn;
  xs[d] = xn;
  __syncthreads();
  float o;
  if (d < 64) {
    float c = cosT[t * 64 + d], s = sinT[t * 64 + d];
    o = xn * c + xs[d + 64] * s;
  } else {
    float c = cosT[t * 64 + d - 64], s = sinT[t * 64 + d - 64];
    o = -xs[d - 64] * s + xn * c;
  }
  qkv[idx] = (_Float16)o;
}

// ---------------- V: transpose qkv v-cols -> (B, 4, 256, T) fp16 ----------------
__global__ void transpose_v(const _Float16* __restrict__ qkv,
                            _Float16* __restrict__ vt) {
  __shared__ _Float16 tile[32][33];
  int t0 = blockIdx.x * 32, d0 = blockIdx.y * 32;
  int bz = blockIdx.z;
  int b = bz >> 2, vh = bz & 3;
  int tx = threadIdx.x, ty = threadIdx.y;
#pragma unroll
  for (int i = 0; i < 4; i++) {
    int t = t0 + ty + i * 8;
    tile[ty + i * 8][tx] = qkv[((size_t)(b * T_SEQ + t)) * NQKV + 3072 + vh * 256 + d0 + tx];
  }
  __syncthreads();
#pragma unroll
  for (int i = 0; i < 4; i++) {
    int d = d0 + ty + i * 8;
    vt[(((size_t)(b * 4 + vh)) * 256 + d) * T_SEQ + t0 + tx] = tile[tx][ty + i * 8];
  }
}

// ---------------- causal flash attention, fp16 MFMA (R4 structure) ----------------
// grid (32 qtiles, 8 heads, 4 = b*2+br), block 256 (4 waves, 16 q-rows each).
__global__ __launch_bounds__(256) void attn(const _Float16* __restrict__ qkv,
                                            const _Float16* __restrict__ vt,
                                            const float* __restrict__ scaler,
                                            float* __restrict__ y1out,
                                            _Float16* __restrict__ y2out) {
  __shared__ _Float16 Kt[64 * 136];     // 17408 B
  __shared__ _Float16 Vt[256 * 72];     // 36864 B, V^T tile [d][s]
  __shared__ _Float16 Pt[4 * 16 * 72];  //  9216 B, per-wave P (A-operand layout)

  int tid = threadIdx.x, lane = tid & 63, w = tid >> 6;
  int l15 = lane & 15, quad = lane >> 4;
  int qt = blockIdx.x, hh = blockIdx.y, z = blockIdx.z;
  int b = z >> 1, br = z & 1;
  int qh = br * 8 + hh;
  int kh = br * 4 + (hh >> 1);
  int vh = hh >> 1;
  int t0 = qt * 64;

  const _Float16* qbase = qkv + ((size_t)(b * T_SEQ + t0)) * NQKV + qh * 128;
  const _Float16* kbase = qkv + ((size_t)(b * T_SEQ)) * NQKV + 2048 + kh * 128;
  const _Float16* vbase = vt + ((size_t)(b * 4 + vh)) * 256 * T_SEQ;

  // Q fragments (A-operand: m = lane&15, k = quad*8+j); row stride NQKV (in place)
  half8 qf[4];
  int qrow = w * 16 + l15;
#pragma unroll
  for (int kc = 0; kc < 4; kc++)
    qf[kc] = *(const half8*)(qbase + (size_t)qrow * NQKV + kc * 32 + quad * 8);

  float mrow[4], lrow[4];
#pragma unroll
  for (int r = 0; r < 4; r++) { mrow[r] = NEG_BIG; lrow[r] = 0.f; }
  f32x4 acc[16];
#pragma unroll
  for (int nb = 0; nb < 16; nb++) acc[nb] = (f32x4){0.f, 0.f, 0.f, 0.f};

  float sc = scaler[qh] * 0.08838834764831844f; // 1/sqrt(128)
  float rowscale[4];
#pragma unroll
  for (int r = 0; r < 4; r++)
    rowscale[r] = sc * logf((float)(t0 + w * 16 + quad * 4 + r + 1));

  int ntiles = qt + 1;
  for (int kt = 0; kt < ntiles; kt++) {
    int ks = kt * 64;
    __syncthreads(); // protect K/V tiles from previous iteration's readers
    // stage K tile: 64 rows x 128 = 1024 chunks of 8
#pragma unroll
    for (int it = 0; it < 4; it++) {
      int idx = it * 256 + tid;
      int r = idx >> 4, c = idx & 15;
      *(half8*)&Kt[r * 136 + c * 8] =
          *(const half8*)(kbase + (size_t)(ks + r) * NQKV + c * 8);
    }
    // stage V^T tile: 256 x 64 = 2048 chunks of 8
#pragma unroll
    for (int it = 0; it < 8; it++) {
      int idx = it * 256 + tid;
      int dd = idx >> 3, c = idx & 7;
      *(half8*)&Vt[dd * 72 + c * 8] =
          *(const half8*)(vbase + (size_t)dd * T_SEQ + ks + c * 8);
    }
    __syncthreads();

    // S = Q K^T
    f32x4 sv[4];
#pragma unroll
    for (int j = 0; j < 4; j++) {
      f32x4 a = (f32x4){0.f, 0.f, 0.f, 0.f};
#pragma unroll
      for (int kc = 0; kc < 4; kc++) {
        half8 kf = *(const half8*)&Kt[(j * 16 + l15) * 136 + kc * 32 + quad * 8];
        a = __builtin_amdgcn_mfma_f32_16x16x32_f16(qf[kc], kf, a, 0, 0, 0);
      }
      sv[j] = a;
    }

    bool diag = (kt == qt);
    float pv[4][4];
#pragma unroll
    for (int r = 0; r < 4; r++) {
      int tg = t0 + w * 16 + quad * 4 + r;
      float mx = NEG_BIG;
      float s_r[4];
#pragma unroll
      for (int j = 0; j < 4; j++) {
        float s = sv[j][r] * rowscale[r];
        int kg = ks + j * 16 + l15;
        if (diag && kg > tg) s = NEG_BIG;
        s_r[j] = s;
        mx = fmaxf(mx, s);
      }
#pragma unroll
      for (int m = 1; m < 16; m <<= 1) mx = fmaxf(mx, __shfl_xor(mx, m, 64));
      float mnew = fmaxf(mrow[r], mx);
      float alpha = expf(mrow[r] - mnew);
      float rs = 0.f;
#pragma unroll
      for (int j = 0; j < 4; j++) {
        float p = expf(s_r[j] - mnew);
        pv[j][r] = p;
        rs += p;
      }
#pragma unroll
      for (int m = 1; m < 16; m <<= 1) rs += __shfl_xor(rs, m, 64);
      lrow[r] = lrow[r] * alpha + rs;
      mrow[r] = mnew;
#pragma unroll
      for (int nb = 0; nb < 16; nb++) acc[nb][r] *= alpha;
    }

    // P (C-layout) -> LDS -> A-operand layout (own wave's slice only)
    _Float16* pw = &Pt[w * 16 * 72];
#pragma unroll
    for (int r = 0; r < 4; r++)
#pragma unroll
      for (int j = 0; j < 4; j++)
        pw[(quad * 4 + r) * 72 + j * 16 + l15] = (_Float16)pv[j][r];

    // O += P V
#pragma unroll
    for (int kc2 = 0; kc2 < 2; kc2++) {
      half8 pf = *(const half8*)&pw[l15 * 72 + kc2 * 32 + quad * 8];
#pragma unroll
      for (int nb = 0; nb < 16; nb++) {
        half8 vf = *(const half8*)&Vt[(nb * 16 + l15) * 72 + kc2 * 32 + quad * 8];
        acc[nb] = __builtin_amdgcn_mfma_f32_16x16x32_f16(pf, vf, acc[nb], 0, 0, 0);
      }
    }
  }

  // epilogue: divide by l; y1 -> d_out f32, y2 -> fp16 workspace. (B,T,8,256)
#pragma unroll
  for (int r = 0; r < 4; r++) {
    int tg = t0 + w * 16 + quad * 4 + r;
    float inv = 1.0f / lrow[r];
    size_t base = ((size_t)(b * T_SEQ + tg)) * 2048 + hh * 256;
    if (br) {
#pragma unroll
      for (int nb = 0; nb < 16; nb++)
        y2out[base + nb * 16 + l15] = (_Float16)(acc[nb][r] * inv);
    } else {
#pragma unroll
      for (int nb = 0; nb < 16; nb++)
        y1out[base + nb * 16 + l15] = acc[nb][r] * inv;
    }
  }
}

// ---------------- out = y1 - lam * y2 (f32, in place on d_out) ----------------
__global__ __launch_bounds__(256) void combine(float* __restrict__ out,
                                               const _Float16* __restrict__ y2,
                                               const float* __restrict__ lq1,
                                               const float* __restrict__ lk1,
                                               const float* __restrict__ lq2,
                                               const float* __restrict__ lk2) {
  int lane = threadIdx.x & 63;
  float a = lq1[lane] * lk1[lane];
  float bb = lq2[lane] * lk2[lane];
#pragma unroll
  for (int m = 1; m < 64; m <<= 1) {
    a += __shfl_xor(a, m, 64);
    bb += __shfl_xor(bb, m, 64);
  }
  float lam = expf(a) - expf(bb) + 0.2f;

  size_t o = ((size_t)blockIdx.x * 256 + threadIdx.x) * 8; // 8,388,608 elems
  half8 yv = *(const half8*)(y2 + o);
  float4 a0 = *(float4*)(out + o);
  float4 a1 = *(float4*)(out + o + 4);
  a0.x -= lam * (float)yv[0];
  a0.y -= lam * (float)yv[1];
  a0.z -= lam * (float)yv[2];
  a0.w -= lam * (float)yv[3];
  a1.x -= lam * (float)yv[4];
  a1.y -= lam * (float)yv[5];
  a1.z -= lam * (float)yv[6];
  a1.w -= lam * (float)yv[7];
  *(float4*)(out + o) = a0;
  *(float4*)(out + o + 4) = a1;
}

extern "C" void kernel_launch(void* const* d_in, const int* in_sizes, int n_in,
                              void* d_out, int out_size, void* d_ws, size_t ws_size,
                              hipStream_t stream) {
  const float* x   = (const float*)d_in[0];
  const float* Wq  = (const float*)d_in[1];
  const float* Wk  = (const float*)d_in[2];
  const float* Wv  = (const float*)d_in[3];
  const float* lq1 = (const float*)d_in[4];
  const float* lk1 = (const float*)d_in[5];
  const float* lq2 = (const float*)d_in[6];
  const float* lk2 = (const float*)d_in[7];
  const float* scaler = (const float*)d_in[8];
  float* out = (float*)d_out;

  char* W = (char*)d_ws;
  // Workspace high-water EXACTLY 64 MiB (proven safe in R4):
  //  [0, 16.78M)      xh fp16   [cvt_x -> gemm]
  //  [16.78M, 33.55M) wh fp16   [cvt_w -> gemm]
  //  [33.55M, 67.11M) qkv fp16  [gemm -> attn] (q/k processed in place)
  //  reuse after gemm:
  //  [0, 8.39M)       vT fp16   [transpose_v -> attn]
  //  [8.39M, 25.17M)  y2 fp16   [attn -> combine]
  // RoPE tables live in d_out[0, 1.05MB) (free until attn writes y1 there).
  _Float16* xh   = (_Float16*)(W + 0);
  _Float16* wh   = (_Float16*)(W + 16777216);
  _Float16* qkvh = (_Float16*)(W + 33554432);
  _Float16* vtb  = (_Float16*)(W + 0);
  _Float16* y2h  = (_Float16*)(W + 8388608);
  float* cosT    = out;            // 2048*64 f32 = 0.52 MB
  float* sinT    = out + 131072;   // 0.52 MB (ends at 1.05 MB < 33.55 MB)

  build_rope<<<T_SEQ, 64, 0, stream>>>(cosT, sinT);
  cvt_x<<<4096, 256, 0, stream>>>(x, xh);
  cvt_w<<<4096, 256, 0, stream>>>(Wq, Wk, Wv, wh);
  gemm_nt<<<dim3(NQKV / 128, MROWS / 128), 256, 0, stream>>>(xh, wh, qkvh);
  postproc<<<dim3(T_SEQ, 24, BSZ), 128, 0, stream>>>(qkvh, cosT, sinT);
  transpose_v<<<dim3(T_SEQ / 32, 256 / 32, BSZ * 4), dim3(32, 8), 0, stream>>>(qkvh, vtb);
  attn<<<dim3(T_SEQ / 64, 8, BSZ * 2), 256, 0, stream>>>(qkvh, vtb, scaler, out, y2h);
  combine<<<4096, 256, 0, stream>>>(out, y2h, lq1, lk1, lq2, lk2);
}

// Round 8
// 695.208 us; speedup vs baseline: 1.4501x; 1.4501x over previous
//
#include <hip/hip_runtime.h>

// Fixed shapes. I/O f32 (proven R7). Intermediates fp16, f32 accum.
#define T_SEQ 2048
#define DMODEL 2048
#define BSZ 2
#define MROWS (BSZ * T_SEQ)   // 4096 tokens
#define NQKV 4096             // 2048 q | 1024 k | 1024 v
#define NEG_BIG (-1e30f)

typedef __attribute__((ext_vector_type(8))) _Float16 half8;  // 16B, 4 VGPRs
typedef __attribute__((ext_vector_type(4))) float f32x4;     // MFMA acc

__device__ __forceinline__ unsigned short f2bf(float f) {
  unsigned u = __float_as_uint(f);
  unsigned r = (u + 0x7fffu + ((u >> 16) & 1u)) >> 16; // RNE
  return (unsigned short)r;
}
__device__ __forceinline__ float bf2f(unsigned short h) {
  return __uint_as_float(((unsigned)h) << 16);
}

// ---------------- RoPE tables (bf16 round-trip like reference) ----------------
// Written into d_out's first 1 MiB (free until attn overwrites it).
__global__ void build_rope(float* __restrict__ cosT, float* __restrict__ sinT) {
  int t = blockIdx.x;    // 0..2047
  int i = threadIdx.x;   // 0..63
  float inv = (float)pow(10000.0, -((double)(2 * i)) / 128.0);
  float fr = (float)t * inv;
  cosT[t * 64 + i] = bf2f(f2bf(cosf(fr)));
  sinT[t * 64 + i] = bf2f(f2bf(sinf(fr)));
}

// ---------------- x (f32) -> fp16 ----------------
__global__ __launch_bounds__(256) void cvt_x(const float* __restrict__ x,
                                             _Float16* __restrict__ xh) {
  size_t o = ((size_t)blockIdx.x * 256 + threadIdx.x) * 8; // 8,388,608 elems
  float4 v0 = *(const float4*)(x + o);
  float4 v1 = *(const float4*)(x + o + 4);
  half8 r;
  r[0] = (_Float16)v0.x; r[1] = (_Float16)v0.y; r[2] = (_Float16)v0.z; r[3] = (_Float16)v0.w;
  r[4] = (_Float16)v1.x; r[5] = (_Float16)v1.y; r[6] = (_Float16)v1.z; r[7] = (_Float16)v1.w;
  *(half8*)(xh + o) = r;
}

// ---------------- [Wq;Wk;Wv] (f32) -> fused (4096,2048) fp16 ----------------
__global__ __launch_bounds__(256) void cvt_w(const float* __restrict__ Wq,
                                             const float* __restrict__ Wk,
                                             const float* __restrict__ Wv,
                                             _Float16* __restrict__ wh) {
  size_t o = ((size_t)blockIdx.x * 256 + threadIdx.x) * 8; // 8,388,608 elems
  int row = (int)(o >> 11), col = (int)(o & 2047);
  const float* src = (row < 2048) ? (Wq + (size_t)row * 2048)
                    : (row < 3072) ? (Wk + (size_t)(row - 2048) * 2048)
                                   : (Wv + (size_t)(row - 3072) * 2048);
  float4 v0 = *(const float4*)(src + col);
  float4 v1 = *(const float4*)(src + col + 4);
  half8 r;
  r[0] = (_Float16)v0.x; r[1] = (_Float16)v0.y; r[2] = (_Float16)v0.z; r[3] = (_Float16)v0.w;
  r[4] = (_Float16)v1.x; r[5] = (_Float16)v1.y; r[6] = (_Float16)v1.z; r[7] = (_Float16)v1.w;
  *(half8*)(wh + o) = r;
}

// ---------------- NT GEMM: qkv[M,4096] = xh[M,K] * wh[4096,K]^T, fp16 in/out ----------------
__global__ __launch_bounds__(256) void gemm_nt(const _Float16* __restrict__ A,
                                               const _Float16* __restrict__ Bw,
                                               _Float16* __restrict__ C) {
  const int K = DMODEL, N = NQKV;
  __shared__ _Float16 At[128 * 40];
  __shared__ _Float16 Bt[128 * 40];
  int tid = threadIdx.x;
  int lane = tid & 63, w = tid >> 6;
  int wm = w >> 1, wn = w & 1;
  int l15 = lane & 15, quad = lane >> 4;
  int bm = blockIdx.y, bn = blockIdx.x;

  f32x4 acc[4][4];
#pragma unroll
  for (int i = 0; i < 4; i++)
#pragma unroll
    for (int j = 0; j < 4; j++) acc[i][j] = (f32x4){0.f, 0.f, 0.f, 0.f};

  for (int k0 = 0; k0 < K; k0 += 32) {
    __syncthreads();
#pragma unroll
    for (int i = 0; i < 2; i++) {
      int idx = i * 256 + tid;          // 512 chunks of 8 elems per tile (128x32)
      int r = idx >> 2, c = idx & 3;
      *(half8*)&At[r * 40 + c * 8] =
          *(const half8*)(A + (size_t)(bm * 128 + r) * K + k0 + c * 8);
      *(half8*)&Bt[r * 40 + c * 8] =
          *(const half8*)(Bw + (size_t)(bn * 128 + r) * K + k0 + c * 8);
    }
    __syncthreads();
    half8 af[4], bfr[4];
#pragma unroll
    for (int i = 0; i < 4; i++)
      af[i] = *(const half8*)&At[(wm * 64 + i * 16 + l15) * 40 + quad * 8];
#pragma unroll
    for (int j = 0; j < 4; j++)
      bfr[j] = *(const half8*)&Bt[(wn * 64 + j * 16 + l15) * 40 + quad * 8];
#pragma unroll
    for (int i = 0; i < 4; i++)
#pragma unroll
      for (int j = 0; j < 4; j++)
        acc[i][j] = __builtin_amdgcn_mfma_f32_16x16x32_f16(af[i], bfr[j], acc[i][j], 0, 0, 0);
  }
#pragma unroll
  for (int i = 0; i < 4; i++)
#pragma unroll
    for (int j = 0; j < 4; j++)
#pragma unroll
      for (int r = 0; r < 4; r++) {
        int row = bm * 128 + wm * 64 + i * 16 + quad * 4 + r; // C/D: row=quad*4+reg
        int col = bn * 128 + wn * 64 + j * 16 + l15;          //       col=lane&15
        C[(size_t)row * N + col] = (_Float16)acc[i][j][r];
      }
}

// ---------------- RMSNorm + RoPE: q in place; k -> packed kp (B,8,T,128) ----------------
__global__ __launch_bounds__(128) void postproc(_Float16* __restrict__ qkv,
                                                const float* __restrict__ cosT,
                                                const float* __restrict__ sinT,
                                                _Float16* __restrict__ kp) {
  int t = blockIdx.x, h = blockIdx.y, b = blockIdx.z;
  int d = threadIdx.x;
  int col = (h < 16) ? (h * 128 + d) : (2048 + (h - 16) * 128 + d);
  size_t idx = ((size_t)(b * T_SEQ + t)) * NQKV + col;
  float v = (float)qkv[idx];
  float ss = v * v;
#pragma unroll
  for (int m = 1; m < 64; m <<= 1) ss += __shfl_xor(ss, m, 64);
  __shared__ float sred[2];
  __shared__ float xs[128];
  if ((threadIdx.x & 63) == 0) sred[threadIdx.x >> 6] = ss;
  __syncthreads();
  float total = sred[0] + sred[1];
  float rn = rsqrtf(total * (1.0f / 128.0f) + 1.1920929e-7f);
  float xn = v * rn;
  xs[d] = xn;
  __syncthreads();
  float o;
  if (d < 64) {
    float c = cosT[t * 64 + d], s = sinT[t * 64 + d];
    o = xn * c + xs[d + 64] * s;
  } else {
    float c = cosT[t * 64 + d - 64], s = sinT[t * 64 + d - 64];
    o = -xs[d - 64] * s + xn * c;
  }
  if (h < 16)
    qkv[idx] = (_Float16)o;
  else
    kp[(((size_t)(b * 8 + (h - 16))) * T_SEQ + t) * 128 + d] = (_Float16)o;
}

// ---------------- V: transpose qkv v-cols -> (B, 4, 256, T) fp16 ----------------
__global__ void transpose_v(const _Float16* __restrict__ qkv,
                            _Float16* __restrict__ vt) {
  __shared__ _Float16 tile[32][33];
  int t0 = blockIdx.x * 32, d0 = blockIdx.y * 32;
  int bz = blockIdx.z;
  int b = bz >> 2, vh = bz & 3;
  int tx = threadIdx.x, ty = threadIdx.y;
#pragma unroll
  for (int i = 0; i < 4; i++) {
    int t = t0 + ty + i * 8;
    tile[ty + i * 8][tx] = qkv[((size_t)(b * T_SEQ + t)) * NQKV + 3072 + vh * 256 + d0 + tx];
  }
  __syncthreads();
#pragma unroll
  for (int i = 0; i < 4; i++) {
    int d = d0 + ty + i * 8;
    vt[(((size_t)(b * 4 + vh)) * 256 + d) * T_SEQ + t0 + tx] = tile[tx][ty + i * 8];
  }
}

// ---------------- causal flash attention v2: barrier-free, global K/V, paired tiles ----------------
// grid (16, 8 heads, 4 = b*2+br), block 256 = 4 independent waves (16 q-rows each).
// Block bx handles q-tiles {bx, 31-bx}: every block does exactly 33 K-tiles.
// K/V fragments read straight from global (L2-resident); only P goes through LDS
// (wave-private slice -> ZERO __syncthreads in this kernel).
__global__ __launch_bounds__(256) void attn(const _Float16* __restrict__ qkv,
                                            const _Float16* __restrict__ kp,
                                            const _Float16* __restrict__ vt,
                                            const float* __restrict__ scaler,
                                            float* __restrict__ y1out,
                                            _Float16* __restrict__ y2out) {
  __shared__ _Float16 Pt[4 * 16 * 72];  // 9216 B, per-wave P (A-operand layout)

  int tid = threadIdx.x, lane = tid & 63, w = tid >> 6;
  int l15 = lane & 15, quad = lane >> 4;
  int bx = blockIdx.x, hh = blockIdx.y, z = blockIdx.z;
  int b = z >> 1, br = z & 1;
  int qh = br * 8 + hh;
  int kh = br * 4 + (hh >> 1);
  int vh = hh >> 1;

  const _Float16* kbase = kp + ((size_t)(b * 8 + kh)) * T_SEQ * 128;
  const _Float16* vbase = vt + ((size_t)(b * 4 + vh)) * 256 * T_SEQ;
  _Float16* pw = &Pt[w * 16 * 72];
  float sc = scaler[qh] * 0.08838834764831844f; // 1/sqrt(128)

  for (int half = 0; half < 2; half++) {
    int qt = half ? (31 - bx) : bx;
    int t0 = qt * 64;

    // Q fragments (A-operand: m = lane&15, k = quad*8+j); q in-place, row stride NQKV
    const _Float16* qbase = qkv + ((size_t)(b * T_SEQ + t0 + w * 16 + l15)) * NQKV + qh * 128;
    half8 qf[4];
#pragma unroll
    for (int kc = 0; kc < 4; kc++)
      qf[kc] = *(const half8*)(qbase + kc * 32 + quad * 8);

    float mrow[4], lrow[4];
#pragma unroll
    for (int r = 0; r < 4; r++) { mrow[r] = NEG_BIG; lrow[r] = 0.f; }
    f32x4 acc[16];
#pragma unroll
    for (int nb = 0; nb < 16; nb++) acc[nb] = (f32x4){0.f, 0.f, 0.f, 0.f};

    float rowscale[4];
#pragma unroll
    for (int r = 0; r < 4; r++)
      rowscale[r] = sc * logf((float)(t0 + w * 16 + quad * 4 + r + 1));

    for (int kt = 0; kt <= qt; kt++) {
      int ks = kt * 64;

      // K fragments direct from global: key = ks + j*16 + l15, d = kc*32 + quad*8
      half8 kf[4][4];
#pragma unroll
      for (int j = 0; j < 4; j++)
#pragma unroll
        for (int kc = 0; kc < 4; kc++)
          kf[j][kc] = *(const half8*)(kbase + (size_t)(ks + j * 16 + l15) * 128 + kc * 32 + quad * 8);

      // S = Q K^T
      f32x4 sv[4];
#pragma unroll
      for (int j = 0; j < 4; j++) {
        f32x4 a = (f32x4){0.f, 0.f, 0.f, 0.f};
#pragma unroll
        for (int kc = 0; kc < 4; kc++)
          a = __builtin_amdgcn_mfma_f32_16x16x32_f16(qf[kc], kf[j][kc], a, 0, 0, 0);
        sv[j] = a;
      }

      bool diag = (kt == qt);
      float pv[4][4];
#pragma unroll
      for (int r = 0; r < 4; r++) {
        int tg = t0 + w * 16 + quad * 4 + r;
        float mx = NEG_BIG;
        float s_r[4];
#pragma unroll
        for (int j = 0; j < 4; j++) {
          float s = sv[j][r] * rowscale[r];
          int kg = ks + j * 16 + l15;
          if (diag && kg > tg) s = NEG_BIG;
          s_r[j] = s;
          mx = fmaxf(mx, s);
        }
#pragma unroll
        for (int m = 1; m < 16; m <<= 1) mx = fmaxf(mx, __shfl_xor(mx, m, 64));
        float mnew = fmaxf(mrow[r], mx);
        float alpha = expf(mrow[r] - mnew);
        float rs = 0.f;
#pragma unroll
        for (int j = 0; j < 4; j++) {
          float p = expf(s_r[j] - mnew);
          pv[j][r] = p;
          rs += p;
        }
#pragma unroll
        for (int m = 1; m < 16; m <<= 1) rs += __shfl_xor(rs, m, 64);
        lrow[r] = lrow[r] * alpha + rs;
        mrow[r] = mnew;
#pragma unroll
        for (int nb = 0; nb < 16; nb++) acc[nb][r] *= alpha;
      }

      // P (C-layout) -> LDS -> A-operand layout (wave-private; no barrier)
#pragma unroll
      for (int r = 0; r < 4; r++)
#pragma unroll
        for (int j = 0; j < 4; j++)
          pw[(quad * 4 + r) * 72 + j * 16 + l15] = (_Float16)pv[j][r];

      // O += P V; V^T fragments direct from global (contiguous along keys)
#pragma unroll
      for (int kc2 = 0; kc2 < 2; kc2++) {
        half8 pf = *(const half8*)&pw[l15 * 72 + kc2 * 32 + quad * 8];
#pragma unroll
        for (int nb = 0; nb < 16; nb++) {
          half8 vf = *(const half8*)(vbase + (size_t)(nb * 16 + l15) * T_SEQ + ks + kc2 * 32 + quad * 8);
          acc[nb] = __builtin_amdgcn_mfma_f32_16x16x32_f16(pf, vf, acc[nb], 0, 0, 0);
        }
      }
    }

    // epilogue: divide by l; y1 -> d_out f32, y2 -> fp16 workspace. (B,T,8,256)
#pragma unroll
    for (int r = 0; r < 4; r++) {
      int tg = t0 + w * 16 + quad * 4 + r;
      float inv = 1.0f / lrow[r];
      size_t base = ((size_t)(b * T_SEQ + tg)) * 2048 + hh * 256;
      if (br) {
#pragma unroll
        for (int nb = 0; nb < 16; nb++)
          y2out[base + nb * 16 + l15] = (_Float16)(acc[nb][r] * inv);
      } else {
#pragma unroll
        for (int nb = 0; nb < 16; nb++)
          y1out[base + nb * 16 + l15] = acc[nb][r] * inv;
      }
    }
  }
}

// ---------------- out = y1 - lam * y2 (f32, in place on d_out) ----------------
__global__ __launch_bounds__(256) void combine(float* __restrict__ out,
                                               const _Float16* __restrict__ y2,
                                               const float* __restrict__ lq1,
                                               const float* __restrict__ lk1,
                                               const float* __restrict__ lq2,
                                               const float* __restrict__ lk2) {
  int lane = threadIdx.x & 63;
  float a = lq1[lane] * lk1[lane];
  float bb = lq2[lane] * lk2[lane];
#pragma unroll
  for (int m = 1; m < 64; m <<= 1) {
    a += __shfl_xor(a, m, 64);
    bb += __shfl_xor(bb, m, 64);
  }
  float lam = expf(a) - expf(bb) + 0.2f;

  size_t o = ((size_t)blockIdx.x * 256 + threadIdx.x) * 8; // 8,388,608 elems
  half8 yv = *(const half8*)(y2 + o);
  float4 a0 = *(float4*)(out + o);
  float4 a1 = *(float4*)(out + o + 4);
  a0.x -= lam * (float)yv[0];
  a0.y -= lam * (float)yv[1];
  a0.z -= lam * (float)yv[2];
  a0.w -= lam * (float)yv[3];
  a1.x -= lam * (float)yv[4];
  a1.y -= lam * (float)yv[5];
  a1.z -= lam * (float)yv[6];
  a1.w -= lam * (float)yv[7];
  *(float4*)(out + o) = a0;
  *(float4*)(out + o + 4) = a1;
}

extern "C" void kernel_launch(void* const* d_in, const int* in_sizes, int n_in,
                              void* d_out, int out_size, void* d_ws, size_t ws_size,
                              hipStream_t stream) {
  const float* x   = (const float*)d_in[0];
  const float* Wq  = (const float*)d_in[1];
  const float* Wk  = (const float*)d_in[2];
  const float* Wv  = (const float*)d_in[3];
  const float* lq1 = (const float*)d_in[4];
  const float* lk1 = (const float*)d_in[5];
  const float* lq2 = (const float*)d_in[6];
  const float* lk2 = (const float*)d_in[7];
  const float* scaler = (const float*)d_in[8];
  float* out = (float*)d_out;

  char* W = (char*)d_ws;
  // Workspace high-water 64 MiB (proven safe):
  // Phase 1 (until gemm done): xh [0,16.78M), wh [16.78,33.55M), qkvh [33.55,67.11M)
  // Phase 2 (after gemm, xh/wh dead): kp [0,8.39M), vtb [8.39,16.78M), y2h [16.78,33.55M)
  // RoPE tables live in d_out[0, 1.05MB) (free until attn writes y1 there).
  _Float16* xh   = (_Float16*)(W + 0);
  _Float16* wh   = (_Float16*)(W + 16777216);
  _Float16* qkvh = (_Float16*)(W + 33554432);
  _Float16* kph  = (_Float16*)(W + 0);
  _Float16* vtb  = (_Float16*)(W + 8388608);
  _Float16* y2h  = (_Float16*)(W + 16777216);
  float* cosT    = out;            // 2048*64 f32 = 0.52 MB
  float* sinT    = out + 131072;   // 0.52 MB (ends at 1.05 MB)

  build_rope<<<T_SEQ, 64, 0, stream>>>(cosT, sinT);
  cvt_x<<<4096, 256, 0, stream>>>(x, xh);
  cvt_w<<<4096, 256, 0, stream>>>(Wq, Wk, Wv, wh);
  gemm_nt<<<dim3(NQKV / 128, MROWS / 128), 256, 0, stream>>>(xh, wh, qkvh);
  postproc<<<dim3(T_SEQ, 24, BSZ), 128, 0, stream>>>(qkvh, cosT, sinT, kph);
  transpose_v<<<dim3(T_SEQ / 32, 256 / 32, BSZ * 4), dim3(32, 8), 0, stream>>>(qkvh, vtb);
  attn<<<dim3(16, 8, BSZ * 2), 256, 0, stream>>>(qkvh, kph, vtb, scaler, out, y2h);
  combine<<<4096, 256, 0, stream>>>(out, y2h, lq1, lk1, lq2, lk2);
}